// Round 14
// baseline (482.889 us; speedup 1.0000x reference)
//
#include <hip/hip_runtime.h>
#include <hip/hip_bf16.h>

#define NM 50000
#define HD 128
#define KNEI 8
#define BM 64
#define SPAD 136
#define NBLK ((NM + BM - 1) / BM)   // 782
#define NH ((size_t)NM * (size_t)HD)

typedef float  fx4   __attribute__((ext_vector_type(4)));
typedef short  s16x8 __attribute__((ext_vector_type(8)));
typedef short  s16x4 __attribute__((ext_vector_type(4)));

__device__ __forceinline__ float sigm_f(float x) {
    return __builtin_amdgcn_rcpf(1.0f + __expf(-x));
}
__device__ __forceinline__ float tanh_f(float x) {
    return 2.0f * sigm_f(2.0f * x) - 1.0f;
}
__device__ __forceinline__ unsigned short f2b(float f) {
    __hip_bfloat16 h = __float2bfloat16(f);
    return __builtin_bit_cast(unsigned short, h);
}
__device__ __forceinline__ float b2f(unsigned short u) {
    __hip_bfloat16 h = __builtin_bit_cast(__hip_bfloat16, u);
    return __bfloat162float(h);
}

#define MFMA16(a, b, c) __builtin_amdgcn_mfma_f32_16x16x32_bf16(a, b, c, 0, 0, 0)

// ---- single-strip B-fragment from global (wave w owns cols w*16..+16) ----
__device__ __forceinline__ void ldb1(const unsigned short* __restrict__ W,
                                     int ldw, int woff, int w, int l, s16x8 (&bf)[4])
{
    const unsigned short* p =
        W + (size_t)(w * 16 + (l & 15)) * ldw + woff + ((l >> 4) << 3);
    #pragma unroll
    for (int ks = 0; ks < 4; ++ks)
        bf[ks] = *(const s16x8*)(p + ks * 32);
}

// acc[rb] += A(rows rb*16..) @ bf^T over K=128 (ks ascending)
__device__ __forceinline__ void pass1(const unsigned short (*As)[SPAD],
                                      const s16x8 (&bf)[4], int l, fx4 (&acc)[4])
{
    const int kq = (l >> 4) << 3;
    #pragma unroll
    for (int ks = 0; ks < 4; ++ks)
        #pragma unroll
        for (int rb = 0; rb < 4; ++rb) {
            const s16x8 a = *(const s16x8*)&As[rb * 16 + (l & 15)][ks * 32 + kq];
            acc[rb] = MFMA16(a, bf[ks], acc[rb]);
        }
}

// ---- 256-thread helpers (pre kernel, unchanged from R13) ----
__device__ __forceinline__ void load_bfrag(const unsigned short* __restrict__ W,
                                           int ldw, int woff, int nf0, int l,
                                           s16x8 (&bf)[2][4])
{
    #pragma unroll
    for (int j = 0; j < 2; ++j) {
        const unsigned short* p =
            W + (size_t)((nf0 + j) * 16 + (l & 15)) * ldw + woff + ((l >> 4) << 3);
        #pragma unroll
        for (int ks = 0; ks < 4; ++ks)
            bf[j][ks] = *(const s16x8*)(p + ks * 32);
    }
}

__device__ __forceinline__ void pass(const unsigned short (*As)[SPAD],
                                     const s16x8 (&bf)[2][4],
                                     int l, fx4 (&acc)[4][2])
{
    const int kq = (l >> 4) << 3;
    #pragma unroll
    for (int ks = 0; ks < 4; ++ks)
        #pragma unroll
        for (int rb = 0; rb < 4; ++rb) {
            const s16x8 a = *(const s16x8*)&As[rb * 16 + (l & 15)][ks * 32 + kq];
            acc[rb][0] = MFMA16(a, bf[0][ks], acc[rb][0]);
            acc[rb][1] = MFMA16(a, bf[1][ks], acc[rb][1]);
        }
}

#define ZACC2(acc) { _Pragma("unroll") for (int z_ = 0; z_ < 4; ++z_) { \
                     acc[z_][0] = (fx4)0.0f; acc[z_][1] = (fx4)0.0f; } }

__device__ __forceinline__ void stage_A32(const float* __restrict__ A, int row0,
                                          unsigned short (*As)[SPAD], int tid)
{
    const int r  = tid & 63;
    const int c0 = (tid >> 6) << 5;
    int gr = row0 + r; if (gr >= NM) gr = NM - 1;
    const float* ap = A + (size_t)gr * HD + c0;
    #pragma unroll
    for (int j = 0; j < 32; j += 8) {
        s16x8 s;
        #pragma unroll
        for (int q = 0; q < 8; ++q) s[q] = (short)f2b(ap[j + q]);
        *(s16x8*)&As[r][c0 + j] = s;
    }
}

__device__ __forceinline__ void lds_to_g16(const unsigned short (*L)[SPAD], int row0,
                                           unsigned short* __restrict__ G, int tid)
{
    const int r  = tid & 63;
    const int c0 = (tid >> 6) << 5;
    const int gr = row0 + r;
    if (gr >= NM) return;
    #pragma unroll
    for (int j = 0; j < 32; j += 8)
        *(s16x8*)&G[(size_t)gr * HD + c0 + j] = *(const s16x8*)&L[r][c0 + j];
}

// ---- 512-thread helpers (iter kernel) ----
__device__ __forceinline__ void stage_A16_512(const unsigned short* __restrict__ A16,
                                              int row0, unsigned short (*As)[SPAD], int tid)
{
    const int r  = tid & 63;
    const int c0 = (tid >> 6) << 4;    // 0..112
    int gr = row0 + r; if (gr >= NM) gr = NM - 1;
    const unsigned short* ap = A16 + (size_t)gr * HD + c0;
    *(s16x8*)&As[r][c0]     = *(const s16x8*)ap;
    *(s16x8*)&As[r][c0 + 8] = *(const s16x8*)(ap + 8);
}

__device__ __forceinline__ void lds_to_g16_512(const unsigned short (*L)[SPAD], int row0,
                                               unsigned short* __restrict__ G, int tid)
{
    const int r  = tid & 63;
    const int c0 = (tid >> 6) << 4;
    const int gr = row0 + r;
    if (gr >= NM) return;
    *(s16x8*)&G[(size_t)gr * HD + c0]     = *(const s16x8*)&L[r][c0];
    *(s16x8*)&G[(size_t)gr * HD + c0 + 8] = *(const s16x8*)&L[r][c0 + 8];
}

// ---------- weight fp32 -> bf16 conversion ----------
__global__ __launch_bounds__(256)
void dgru_wcvt(const float* __restrict__ Wz, const float* __restrict__ Wr,
               const float* __restrict__ Ur, const float* __restrict__ Wh,
               unsigned short* __restrict__ w16)
{
    const int i = blockIdx.x * 256 + threadIdx.x;
    float v;
    if      (i < 32768) v = Wz[i];
    else if (i < 49152) v = Wr[i - 32768];
    else if (i < 65536) v = Ur[i - 49152];
    else                v = Wh[i - 65536];
    w16[i] = f2b(v);
}

// ---------- pre (R13 verbatim): fmess16 + pre_r16 + h0 + Uh0 ----------
__global__ __launch_bounds__(256, 3)
void dgru_pre(const float* __restrict__ fmess,
              const unsigned short* __restrict__ wz16,
              const unsigned short* __restrict__ wr16,
              const unsigned short* __restrict__ wh16,
              const unsigned short* __restrict__ ur16,
              const float* __restrict__ bz, const float* __restrict__ bh,
              const float* __restrict__ bur,
              unsigned short* __restrict__ fmess16,
              unsigned short* __restrict__ pre_r16,
              unsigned short* __restrict__ h16, unsigned short* __restrict__ uh16)
{
    __shared__ unsigned short AsF[BM][SPAD];
    __shared__ unsigned short AsX[BM][SPAD];
    const int tid  = threadIdx.x;
    const int row0 = blockIdx.x * BM;
    const int l    = tid & 63;
    const int nf0  = (tid >> 6) << 1;
    const int col0 = nf0 * 16 + (l & 15);
    const int rq   = (l >> 4) << 2;

    s16x8 bfA[2][4], bfB[2][4];
    load_bfrag(wz16, 2 * HD, 0, nf0, l, bfA);   // Wz1
    load_bfrag(wr16, HD, 0, nf0, l, bfB);       // Wr
    stage_A32(fmess, row0, AsF, tid);
    __syncthreads();                            // S1

    lds_to_g16(AsF, row0, fmess16, tid);        // persist bf16 fmess

    fx4 zacc[4][2]; ZACC2(zacc);
    pass(AsF, bfA, l, zacc);                    // fmess @ Wz1
    load_bfrag(wh16, 2 * HD, 0, nf0, l, bfA);   // Wh1
    {
        fx4 racc[4][2]; ZACC2(racc);
        pass(AsF, bfB, l, racc);                // fmess @ Wr
        #pragma unroll
        for (int rb = 0; rb < 4; ++rb)
            #pragma unroll
            for (int j = 0; j < 2; ++j)
                #pragma unroll
                for (int q = 0; q < 4; ++q)
                    AsX[rb * 16 + rq + q][col0 + j * 16] = f2b(racc[rb][j][q]);
    }
    __syncthreads();                            // S2
    lds_to_g16(AsX, row0, pre_r16, tid);

    fx4 hacc[4][2]; ZACC2(hacc);
    pass(AsF, bfA, l, hacc);                    // fmess @ Wh1
    load_bfrag(ur16, HD, 0, nf0, l, bfB);       // Ur
    #pragma unroll
    for (int rb = 0; rb < 4; ++rb)
        #pragma unroll
        for (int j = 0; j < 2; ++j) {
            const float bvz = bz[col0 + j * 16];
            const float bvh = bh[col0 + j * 16];
            #pragma unroll
            for (int q = 0; q < 4; ++q) {
                const int gr = row0 + rb * 16 + rq + q;
                float h0 = sigm_f(zacc[rb][j][q] + bvz) * tanh_f(hacc[rb][j][q] + bvh);
                if (gr == 0) h0 = 0.0f;
                hacc[rb][j][q] = h0;
            }
        }
    __syncthreads();                            // S3
    #pragma unroll
    for (int rb = 0; rb < 4; ++rb)
        #pragma unroll
        for (int j = 0; j < 2; ++j)
            #pragma unroll
            for (int q = 0; q < 4; ++q)
                AsX[rb * 16 + rq + q][col0 + j * 16] = f2b(hacc[rb][j][q]);
    __syncthreads();                            // S4
    lds_to_g16(AsX, row0, h16, tid);
    {
        fx4 uacc[4][2]; ZACC2(uacc);
        pass(AsX, bfB, l, uacc);                // h0 @ Ur
        #pragma unroll
        for (int rb = 0; rb < 4; ++rb)
            #pragma unroll
            for (int j = 0; j < 2; ++j) {
                const float bv = bur[col0 + j * 16];
                #pragma unroll
                for (int q = 0; q < 4; ++q)
                    AsF[rb * 16 + rq + q][col0 + j * 16] = f2b(uacc[rb][j][q] + bv);
            }
    }
    __syncthreads();                            // S5
    lds_to_g16(AsF, row0, uh16, tid);
}

// ---------- iter: fused gather + z + GRU update + next Uh (512 thr, 8 waves) ----------
// Reads h16r/uh16r (iter t), writes h16w/uh16w (iter t+1): ping-pong, race-free.
__global__ __launch_bounds__(512, 4)
void dgru_iter(const int* __restrict__ bgraph,
               const unsigned short* __restrict__ pre_r16,
               const unsigned short* __restrict__ fmess16,
               const unsigned short* __restrict__ wz16,
               const unsigned short* __restrict__ wh16,
               const unsigned short* __restrict__ ur16,
               const float* __restrict__ bz, const float* __restrict__ bh,
               const float* __restrict__ bur,
               const unsigned short* __restrict__ h16r,
               const unsigned short* __restrict__ uh16r,
               unsigned short* __restrict__ h16w,
               unsigned short* __restrict__ uh16w,
               float* __restrict__ hout, int last)
{
    __shared__ unsigned short AsF[BM][SPAD];   // fmess tile; later new h
    __shared__ unsigned short AsH[BM][SPAD];   // gathered sum_h; later new Uh
    __shared__ unsigned short AsG[BM][SPAD];   // gathered sum_gated
    const int tid  = threadIdx.x;
    const int row0 = blockIdx.x * BM;
    const int w    = tid >> 6;                 // wave 0..7 -> col strip w*16
    const int l    = tid & 63;
    const int col0 = w * 16 + (l & 15);
    const int rq   = (l >> 4) << 2;

    // ---- gather phase: 8 threads/msg, 16 dims each, sums -> LDS tiles ----
    {
        const int m  = tid >> 3;               // 0..63
        const int d0 = (tid & 7) << 4;         // 0..112
        int n = row0 + m; if (n >= NM) n = NM - 1;

        const int4* bg = (const int4*)(bgraph + (size_t)n * KNEI);
        const int4 bA = bg[0], bB = bg[1];
        const int idx[KNEI] = {bA.x, bA.y, bA.z, bA.w, bB.x, bB.y, bB.z, bB.w};

        float pr[16];
        {
            const unsigned short* p = pre_r16 + (size_t)n * HD + d0;
            const s16x8 a = *(const s16x8*)p;
            const s16x8 b = *(const s16x8*)(p + 8);
            #pragma unroll
            for (int j = 0; j < 8; ++j) {
                pr[j]     = b2f((unsigned short)a[j]);
                pr[8 + j] = b2f((unsigned short)b[j]);
            }
        }
        float sh[16], sg[16];
        #pragma unroll
        for (int j = 0; j < 16; ++j) { sh[j] = 0.0f; sg[j] = 0.0f; }

        #pragma unroll
        for (int k = 0; k < KNEI; ++k) {       // k ascending: same FP order as before
            const unsigned short* hp = h16r  + (size_t)idx[k] * HD + d0;
            const unsigned short* up = uh16r + (size_t)idx[k] * HD + d0;
            const s16x8 h0 = *(const s16x8*)hp, h1 = *(const s16x8*)(hp + 8);
            const s16x8 u0 = *(const s16x8*)up, u1 = *(const s16x8*)(up + 8);
            #pragma unroll
            for (int j = 0; j < 8; ++j) {
                const float hv = b2f((unsigned short)h0[j]);
                const float uv = b2f((unsigned short)u0[j]);
                sh[j] += hv;
                sg[j] = fmaf(sigm_f(pr[j] + uv), hv, sg[j]);
            }
            #pragma unroll
            for (int j = 0; j < 8; ++j) {
                const float hv = b2f((unsigned short)h1[j]);
                const float uv = b2f((unsigned short)u1[j]);
                sh[8 + j] += hv;
                sg[8 + j] = fmaf(sigm_f(pr[8 + j] + uv), hv, sg[8 + j]);
            }
        }
        s16x8 o0, o1, g0, g1;
        #pragma unroll
        for (int j = 0; j < 8; ++j) {
            o0[j] = (short)f2b(sh[j]);     o1[j] = (short)f2b(sh[8 + j]);
            g0[j] = (short)f2b(sg[j]);     g1[j] = (short)f2b(sg[8 + j]);
        }
        *(s16x8*)&AsH[m][d0]     = o0;
        *(s16x8*)&AsH[m][d0 + 8] = o1;
        *(s16x8*)&AsG[m][d0]     = g0;
        *(s16x8*)&AsG[m][d0 + 8] = g1;
    }
    stage_A16_512(fmess16, row0, AsF, tid);
    __syncthreads();                            // S1: all three tiles ready

    // ---- z = sigmoid(fmess@Wz1 + sum_h@Wz2 + bz) ----
    s16x8 bfA[4], bfB[4];
    ldb1(wz16, 2 * HD, 0,  w, l, bfA);
    ldb1(wz16, 2 * HD, HD, w, l, bfB);
    fx4 zacc[4];
    #pragma unroll
    for (int rb = 0; rb < 4; ++rb) zacc[rb] = (fx4)0.0f;
    pass1(AsF, bfA, l, zacc);
    pass1(AsH, bfB, l, zacc);
    float shv[4][4];
    {
        const float bv = bz[col0];
        #pragma unroll
        for (int rb = 0; rb < 4; ++rb)
            #pragma unroll
            for (int q = 0; q < 4; ++q) {
                shv[rb][q] = b2f(AsH[rb * 16 + rq + q][col0]);
                zacc[rb][q] = sigm_f(zacc[rb][q] + bv);    // zacc := z
            }
    }

    // ---- h = (1-z)*sum_h + z*tanh(fmess@Wh1 + sum_g@Wh2 + bh) ----
    ldb1(wh16, 2 * HD, 0,  w, l, bfA);
    ldb1(wh16, 2 * HD, HD, w, l, bfB);
    fx4 hacc[4];
    #pragma unroll
    for (int rb = 0; rb < 4; ++rb) hacc[rb] = (fx4)0.0f;
    pass1(AsF, bfA, l, hacc);
    pass1(AsG, bfB, l, hacc);
    {
        const float bv = bh[col0];
        #pragma unroll
        for (int rb = 0; rb < 4; ++rb)
            #pragma unroll
            for (int q = 0; q < 4; ++q) {
                const int gr = row0 + rb * 16 + rq + q;
                const float zz = zacc[rb][q];
                float o = (1.0f - zz) * shv[rb][q] + zz * tanh_f(hacc[rb][q] + bv);
                if (gr == 0) o = 0.0f;
                hacc[rb][q] = o;
            }
    }
    if (last) {
        #pragma unroll
        for (int rb = 0; rb < 4; ++rb)
            #pragma unroll
            for (int q = 0; q < 4; ++q) {
                const int gr = row0 + rb * 16 + rq + q;
                if (gr < NM) hout[(size_t)gr * HD + col0] = hacc[rb][q];
            }
        return;
    }

    ldb1(ur16, HD, 0, w, l, bfA);               // Ur
    __syncthreads();                            // S2: all tile readers done
    #pragma unroll
    for (int rb = 0; rb < 4; ++rb)
        #pragma unroll
        for (int q = 0; q < 4; ++q)
            AsF[rb * 16 + rq + q][col0] = f2b(hacc[rb][q]);   // new h into AsF
    __syncthreads();                            // S3
    lds_to_g16_512(AsF, row0, h16w, tid);

    // ---- Uh = h @ Ur + bur ----
    fx4 uacc[4];
    #pragma unroll
    for (int rb = 0; rb < 4; ++rb) uacc[rb] = (fx4)0.0f;
    pass1(AsF, bfA, l, uacc);
    {
        const float bv = bur[col0];
        #pragma unroll
        for (int rb = 0; rb < 4; ++rb)
            #pragma unroll
            for (int q = 0; q < 4; ++q)
                AsH[rb * 16 + rq + q][col0] = f2b(uacc[rb][q] + bv);  // into AsH
    }
    __syncthreads();                            // S4
    lds_to_g16_512(AsH, row0, uh16w, tid);
}

extern "C" void kernel_launch(void* const* d_in, const int* in_sizes, int n_in,
                              void* d_out, int out_size, void* d_ws, size_t ws_size,
                              hipStream_t stream) {
    const float* fmess  = (const float*)d_in[0];
    const int*   bgraph = (const int*)  d_in[1];
    const float* W_z    = (const float*)d_in[2];
    const float* b_z    = (const float*)d_in[3];
    const float* W_r    = (const float*)d_in[4];
    const float* U_r    = (const float*)d_in[5];
    const float* b_Ur   = (const float*)d_in[6];
    const float* W_h    = (const float*)d_in[7];
    const float* b_h    = (const float*)d_in[8];

    unsigned short* ws16 = (unsigned short*)d_ws;
    unsigned short* fmess16 = ws16;
    unsigned short* pre_r16 = ws16 + NH;
    unsigned short* h16a    = ws16 + 2 * NH;
    unsigned short* uh16a   = ws16 + 3 * NH;
    unsigned short* h16b    = ws16 + 4 * NH;
    unsigned short* uh16b   = ws16 + 5 * NH;
    unsigned short* w16     = ws16 + 6 * NH;
    unsigned short* wz16 = w16;                // [128][256]
    unsigned short* wr16 = w16 + 32768;        // [128][128]
    unsigned short* ur16 = w16 + 49152;        // [128][128]
    unsigned short* wh16 = w16 + 65536;        // [128][256]
    float* hout = (float*)d_out;
    // ws usage ~= 77 MB

    dgru_wcvt<<<dim3(384), dim3(256), 0, stream>>>(W_z, W_r, U_r, W_h, w16);

    dgru_pre<<<dim3(NBLK), dim3(256), 0, stream>>>(
        fmess, wz16, wr16, wh16, ur16, b_z, b_h, b_Ur,
        fmess16, pre_r16, h16a, uh16a);

    for (int it = 1; it < 5; ++it) {
        const int pa = (it & 1);               // odd: read A write B; even: read B write A
        const unsigned short* hr = pa ? h16a : h16b;
        const unsigned short* ur = pa ? uh16a : uh16b;
        unsigned short* hw = pa ? h16b : h16a;
        unsigned short* uw = pa ? uh16b : uh16a;
        dgru_iter<<<dim3(NBLK), dim3(512), 0, stream>>>(
            bgraph, pre_r16, fmess16, wz16, wh16, ur16, b_z, b_h, b_Ur,
            hr, ur, hw, uw, hout, (it == 4) ? 1 : 0);
    }
}

// Round 17
// 384.410 us; speedup vs baseline: 1.2562x; 1.2562x over previous
//
#include <hip/hip_runtime.h>
#include <hip/hip_bf16.h>

#define NM 50000
#define HD 128
#define KNEI 8
#define BM 64
#define SPAD 136
#define NBLK ((NM + BM - 1) / BM)   // 782
#define NH ((size_t)NM * (size_t)HD)

typedef float  fx4   __attribute__((ext_vector_type(4)));
typedef short  s16x8 __attribute__((ext_vector_type(8)));
typedef short  s16x4 __attribute__((ext_vector_type(4)));

__device__ __forceinline__ float sigm_f(float x) {
    return __builtin_amdgcn_rcpf(1.0f + __expf(-x));
}
__device__ __forceinline__ float tanh_f(float x) {
    return 2.0f * sigm_f(2.0f * x) - 1.0f;
}
__device__ __forceinline__ unsigned short f2b(float f) {
    __hip_bfloat16 h = __float2bfloat16(f);
    return __builtin_bit_cast(unsigned short, h);
}
__device__ __forceinline__ float b2f(unsigned short u) {
    __hip_bfloat16 h = __builtin_bit_cast(__hip_bfloat16, u);
    return __bfloat162float(h);
}

#define MFMA16(a, b, c) __builtin_amdgcn_mfma_f32_16x16x32_bf16(a, b, c, 0, 0, 0)

// ---- register B-fragments from global (L2-hot weights) ----
__device__ __forceinline__ void load_bfrag(const unsigned short* __restrict__ W,
                                           int ldw, int woff, int nf0, int l,
                                           s16x8 (&bf)[2][4])
{
    #pragma unroll
    for (int j = 0; j < 2; ++j) {
        const unsigned short* p =
            W + (size_t)((nf0 + j) * 16 + (l & 15)) * ldw + woff + ((l >> 4) << 3);
        #pragma unroll
        for (int ks = 0; ks < 4; ++ks)
            bf[j][ks] = *(const s16x8*)(p + ks * 32);
    }
}

// acc[rb][j] += A_tile(LDS) @ bf[j]^T over K=128 (ks ascending)
__device__ __forceinline__ void pass(const unsigned short (*As)[SPAD],
                                     const s16x8 (&bf)[2][4],
                                     int l, fx4 (&acc)[4][2])
{
    const int kq = (l >> 4) << 3;
    #pragma unroll
    for (int ks = 0; ks < 4; ++ks)
        #pragma unroll
        for (int rb = 0; rb < 4; ++rb) {
            const s16x8 a = *(const s16x8*)&As[rb * 16 + (l & 15)][ks * 32 + kq];
            acc[rb][0] = MFMA16(a, bf[0][ks], acc[rb][0]);
            acc[rb][1] = MFMA16(a, bf[1][ks], acc[rb][1]);
        }
}

// acc[rb][j] += A(global row-major bf16, rows row0..row0+63) @ bf[j]^T  — no LDS
// NOTE: rows >= NM read garbage inside d_ws (guarded at store); safe.
__device__ __forceinline__ void pass_g(const unsigned short* __restrict__ A, int row0,
                                       const s16x8 (&bf)[2][4],
                                       int l, fx4 (&acc)[4][2])
{
    const unsigned short* p = A + (size_t)(row0 + (l & 15)) * HD + ((l >> 4) << 3);
    #pragma unroll
    for (int ks = 0; ks < 4; ++ks)
        #pragma unroll
        for (int rb = 0; rb < 4; ++rb) {
            const s16x8 a = *(const s16x8*)(p + rb * 16 * HD + ks * 32);
            acc[rb][0] = MFMA16(a, bf[0][ks], acc[rb][0]);
            acc[rb][1] = MFMA16(a, bf[1][ks], acc[rb][1]);
        }
}

#define ZACC2(acc) { _Pragma("unroll") for (int z_ = 0; z_ < 4; ++z_) { \
                     acc[z_][0] = (fx4)0.0f; acc[z_][1] = (fx4)0.0f; } }

// ---- 256-thread A staging / writeback ----
__device__ __forceinline__ void stage_A32(const float* __restrict__ A, int row0,
                                          unsigned short (*As)[SPAD], int tid)
{
    const int r  = tid & 63;
    const int c0 = (tid >> 6) << 5;
    int gr = row0 + r; if (gr >= NM) gr = NM - 1;
    const float* ap = A + (size_t)gr * HD + c0;
    #pragma unroll
    for (int j = 0; j < 32; j += 8) {
        s16x8 s;
        #pragma unroll
        for (int q = 0; q < 8; ++q) s[q] = (short)f2b(ap[j + q]);
        *(s16x8*)&As[r][c0 + j] = s;
    }
}

__device__ __forceinline__ void lds_to_g16(const unsigned short (*L)[SPAD], int row0,
                                           unsigned short* __restrict__ G, int tid)
{
    const int r  = tid & 63;
    const int c0 = (tid >> 6) << 5;
    const int gr = row0 + r;
    if (gr >= NM) return;
    #pragma unroll
    for (int j = 0; j < 32; j += 8)
        *(s16x8*)&G[(size_t)gr * HD + c0 + j] = *(const s16x8*)&L[r][c0 + j];
}

// ---------- weight fp32 -> bf16 conversion ----------
__global__ __launch_bounds__(256)
void dgru_wcvt(const float* __restrict__ Wz, const float* __restrict__ Wr,
               const float* __restrict__ Ur, const float* __restrict__ Wh,
               unsigned short* __restrict__ w16)
{
    const int i = blockIdx.x * 256 + threadIdx.x;
    float v;
    if      (i < 32768) v = Wz[i];
    else if (i < 49152) v = Wr[i - 32768];
    else if (i < 65536) v = Ur[i - 49152];
    else                v = Wh[i - 65536];
    w16[i] = f2b(v);
}

// ---------- pre (R13 verbatim): fmess16 + pre_r16 + h0 + Uh0 ----------
__global__ __launch_bounds__(256, 3)
void dgru_pre(const float* __restrict__ fmess,
              const unsigned short* __restrict__ wz16,
              const unsigned short* __restrict__ wr16,
              const unsigned short* __restrict__ wh16,
              const unsigned short* __restrict__ ur16,
              const float* __restrict__ bz, const float* __restrict__ bh,
              const float* __restrict__ bur,
              unsigned short* __restrict__ fmess16,
              unsigned short* __restrict__ pre_r16,
              unsigned short* __restrict__ h16, unsigned short* __restrict__ uh16)
{
    __shared__ unsigned short AsF[BM][SPAD];
    __shared__ unsigned short AsX[BM][SPAD];
    const int tid  = threadIdx.x;
    const int row0 = blockIdx.x * BM;
    const int l    = tid & 63;
    const int nf0  = (tid >> 6) << 1;
    const int col0 = nf0 * 16 + (l & 15);
    const int rq   = (l >> 4) << 2;

    s16x8 bfA[2][4], bfB[2][4];
    load_bfrag(wz16, 2 * HD, 0, nf0, l, bfA);   // Wz1
    load_bfrag(wr16, HD, 0, nf0, l, bfB);       // Wr
    stage_A32(fmess, row0, AsF, tid);
    __syncthreads();                            // S1

    lds_to_g16(AsF, row0, fmess16, tid);        // persist bf16 fmess

    fx4 zacc[4][2]; ZACC2(zacc);
    pass(AsF, bfA, l, zacc);                    // fmess @ Wz1
    load_bfrag(wh16, 2 * HD, 0, nf0, l, bfA);   // Wh1
    {
        fx4 racc[4][2]; ZACC2(racc);
        pass(AsF, bfB, l, racc);                // fmess @ Wr
        #pragma unroll
        for (int rb = 0; rb < 4; ++rb)
            #pragma unroll
            for (int j = 0; j < 2; ++j)
                #pragma unroll
                for (int q = 0; q < 4; ++q)
                    AsX[rb * 16 + rq + q][col0 + j * 16] = f2b(racc[rb][j][q]);
    }
    __syncthreads();                            // S2
    lds_to_g16(AsX, row0, pre_r16, tid);

    fx4 hacc[4][2]; ZACC2(hacc);
    pass(AsF, bfA, l, hacc);                    // fmess @ Wh1
    load_bfrag(ur16, HD, 0, nf0, l, bfB);       // Ur
    #pragma unroll
    for (int rb = 0; rb < 4; ++rb)
        #pragma unroll
        for (int j = 0; j < 2; ++j) {
            const float bvz = bz[col0 + j * 16];
            const float bvh = bh[col0 + j * 16];
            #pragma unroll
            for (int q = 0; q < 4; ++q) {
                const int gr = row0 + rb * 16 + rq + q;
                float h0 = sigm_f(zacc[rb][j][q] + bvz) * tanh_f(hacc[rb][j][q] + bvh);
                if (gr == 0) h0 = 0.0f;
                hacc[rb][j][q] = h0;
            }
        }
    __syncthreads();                            // S3
    #pragma unroll
    for (int rb = 0; rb < 4; ++rb)
        #pragma unroll
        for (int j = 0; j < 2; ++j)
            #pragma unroll
            for (int q = 0; q < 4; ++q)
                AsX[rb * 16 + rq + q][col0 + j * 16] = f2b(hacc[rb][j][q]);
    __syncthreads();                            // S4
    lds_to_g16(AsX, row0, h16, tid);
    {
        fx4 uacc[4][2]; ZACC2(uacc);
        pass(AsX, bfB, l, uacc);                // h0 @ Ur
        #pragma unroll
        for (int rb = 0; rb < 4; ++rb)
            #pragma unroll
            for (int j = 0; j < 2; ++j) {
                const float bv = bur[col0 + j * 16];
                #pragma unroll
                for (int q = 0; q < 4; ++q)
                    AsF[rb * 16 + rq + q][col0 + j * 16] = f2b(uacc[rb][j][q] + bv);
            }
    }
    __syncthreads();                            // S5
    lds_to_g16(AsF, row0, uh16, tid);
}

// ---------- gather (R13 verbatim, standalone high-occupancy) ----------
__global__ __launch_bounds__(256)
void dgru_gather(const unsigned short* __restrict__ h16,
                 const unsigned short* __restrict__ uh16,
                 const int* __restrict__ bgraph,
                 const unsigned short* __restrict__ pre_r16,
                 unsigned short* __restrict__ sh16, unsigned short* __restrict__ sg16)
{
    const int tid = threadIdx.x;
    const int n   = blockIdx.x * 8 + (tid >> 5);
    const int d0  = (tid & 31) << 2;

    const int4* bg = (const int4*)(bgraph + (size_t)n * KNEI);
    const int4 b0 = bg[0], b1 = bg[1];
    const int idx[KNEI] = {b0.x, b0.y, b0.z, b0.w, b1.x, b1.y, b1.z, b1.w};

    s16x4 hr[KNEI], ur[KNEI];
    #pragma unroll
    for (int k = 0; k < KNEI; ++k)
        hr[k] = *(const s16x4*)&h16[(size_t)idx[k] * HD + d0];
    #pragma unroll
    for (int k = 0; k < KNEI; ++k)
        ur[k] = *(const s16x4*)&uh16[(size_t)idx[k] * HD + d0];
    const s16x4 prb = *(const s16x4*)&pre_r16[(size_t)n * HD + d0];
    float pr[4];
    #pragma unroll
    for (int j = 0; j < 4; ++j) pr[j] = b2f((unsigned short)prb[j]);

    float sh[4] = {0.f, 0.f, 0.f, 0.f};
    float sg[4] = {0.f, 0.f, 0.f, 0.f};
    #pragma unroll
    for (int k = 0; k < KNEI; ++k) {
        #pragma unroll
        for (int j = 0; j < 4; ++j) {
            const float hv = b2f((unsigned short)hr[k][j]);
            const float uv = b2f((unsigned short)ur[k][j]);
            sh[j] += hv;
            sg[j] = fmaf(sigm_f(pr[j] + uv), hv, sg[j]);
        }
    }
    s16x4 osh, osg;
    #pragma unroll
    for (int j = 0; j < 4; ++j) {
        osh[j] = (short)f2b(sh[j]);
        osg[j] = (short)f2b(sg[j]);
    }
    const size_t o = (size_t)n * HD + d0;
    *(s16x4*)&sh16[o] = osh;
    *(s16x4*)&sg16[o] = osg;
}

// ---------- zh: global A-fragments, 2 barriers; z + GRU update + next Uh ----------
__global__ __launch_bounds__(256, 3)
void dgru_zh(const unsigned short* __restrict__ fmess16,
             const unsigned short* __restrict__ sh16,
             const unsigned short* __restrict__ sg16,
             const unsigned short* __restrict__ wz16,
             const unsigned short* __restrict__ wh16,
             const unsigned short* __restrict__ ur16,
             const float* __restrict__ bz, const float* __restrict__ bh,
             const float* __restrict__ bur,
             unsigned short* __restrict__ h16, unsigned short* __restrict__ uh16,
             float* __restrict__ hout, int last)
{
    __shared__ unsigned short AsF[BM][SPAD];   // new-h exchange tile
    __shared__ unsigned short AsX[BM][SPAD];   // Uh exchange tile
    const int tid  = threadIdx.x;
    const int row0 = blockIdx.x * BM;
    const int l    = tid & 63;
    const int nf0  = (tid >> 6) << 1;
    const int col0 = nf0 * 16 + (l & 15);
    const int rq   = (l >> 4) << 2;

    s16x8 bfA[2][4], bfB[2][4];
    load_bfrag(wz16, 2 * HD, 0,  nf0, l, bfA);  // Wz1
    load_bfrag(wz16, 2 * HD, HD, nf0, l, bfB);  // Wz2

    // ---- z = sigmoid(fmess@Wz1 + sum_h@Wz2 + bz)  (all A-frags from global) ----
    fx4 zacc[4][2]; ZACC2(zacc);
    pass_g(fmess16, row0, bfA, l, zacc);
    pass_g(sh16,    row0, bfB, l, zacc);
    load_bfrag(wh16, 2 * HD, 0,  nf0, l, bfA);  // Wh1
    load_bfrag(wh16, 2 * HD, HD, nf0, l, bfB);  // Wh2
    #pragma unroll
    for (int rb = 0; rb < 4; ++rb)
        #pragma unroll
        for (int j = 0; j < 2; ++j) {
            const float bv = bz[col0 + j * 16];
            #pragma unroll
            for (int q = 0; q < 4; ++q)
                zacc[rb][j][q] = sigm_f(zacc[rb][j][q] + bv);   // zacc := z
        }

    // ---- h = (1-z)*sum_h + z*tanh(fmess@Wh1 + sum_g@Wh2 + bh) ----
    fx4 hacc[4][2]; ZACC2(hacc);
    pass_g(fmess16, row0, bfA, l, hacc);
    pass_g(sg16,    row0, bfB, l, hacc);
    #pragma unroll
    for (int rb = 0; rb < 4; ++rb)
        #pragma unroll
        for (int j = 0; j < 2; ++j) {
            const float bv = bh[col0 + j * 16];
            #pragma unroll
            for (int q = 0; q < 4; ++q) {
                const int gr = row0 + rb * 16 + rq + q;
                const int cr = (gr < NM) ? gr : (NM - 1);
                const float sv = b2f(sh16[(size_t)cr * HD + col0 + j * 16]); // same bytes as LDS path
                const float zz = zacc[rb][j][q];
                float o = (1.0f - zz) * sv + zz * tanh_f(hacc[rb][j][q] + bv);
                if (gr == 0) o = 0.0f;
                hacc[rb][j][q] = o;
            }
        }
    if (last) {
        #pragma unroll
        for (int rb = 0; rb < 4; ++rb)
            #pragma unroll
            for (int j = 0; j < 2; ++j)
                #pragma unroll
                for (int q = 0; q < 4; ++q) {
                    const int gr = row0 + rb * 16 + rq + q;
                    if (gr < NM) hout[(size_t)gr * HD + col0 + j * 16] = hacc[rb][j][q];
                }
        return;
    }

    load_bfrag(ur16, HD, 0, nf0, l, bfA);       // Ur
    #pragma unroll
    for (int rb = 0; rb < 4; ++rb)
        #pragma unroll
        for (int j = 0; j < 2; ++j)
            #pragma unroll
            for (int q = 0; q < 4; ++q)
                AsF[rb * 16 + rq + q][col0 + j * 16] = f2b(hacc[rb][j][q]);
    __syncthreads();                            // S1: new-h tile complete
    lds_to_g16(AsF, row0, h16, tid);
    {
        fx4 uacc[4][2]; ZACC2(uacc);
        pass(AsF, bfA, l, uacc);                // h @ Ur (LDS A-frags)
        #pragma unroll
        for (int rb = 0; rb < 4; ++rb)
            #pragma unroll
            for (int j = 0; j < 2; ++j) {
                const float bv = bur[col0 + j * 16];
                #pragma unroll
                for (int q = 0; q < 4; ++q)
                    AsX[rb * 16 + rq + q][col0 + j * 16] = f2b(uacc[rb][j][q] + bv);
            }
    }
    __syncthreads();                            // S2: Uh tile complete
    lds_to_g16(AsX, row0, uh16, tid);
}

extern "C" void kernel_launch(void* const* d_in, const int* in_sizes, int n_in,
                              void* d_out, int out_size, void* d_ws, size_t ws_size,
                              hipStream_t stream) {
    const float* fmess  = (const float*)d_in[0];
    const int*   bgraph = (const int*)  d_in[1];
    const float* W_z    = (const float*)d_in[2];
    const float* b_z    = (const float*)d_in[3];
    const float* W_r    = (const float*)d_in[4];
    const float* U_r    = (const float*)d_in[5];
    const float* b_Ur   = (const float*)d_in[6];
    const float* W_h    = (const float*)d_in[7];
    const float* b_h    = (const float*)d_in[8];

    unsigned short* ws16 = (unsigned short*)d_ws;
    unsigned short* fmess16 = ws16;
    unsigned short* pre_r16 = ws16 + NH;
    unsigned short* h16     = ws16 + 2 * NH;
    unsigned short* uh16    = ws16 + 3 * NH;
    unsigned short* sh16    = ws16 + 4 * NH;
    unsigned short* sg16    = ws16 + 5 * NH;
    unsigned short* w16     = ws16 + 6 * NH;
    unsigned short* wz16 = w16;                // [128][256]
    unsigned short* wr16 = w16 + 32768;        // [128][128]
    unsigned short* ur16 = w16 + 49152;        // [128][128]
    unsigned short* wh16 = w16 + 65536;        // [128][256]
    float* hout = (float*)d_out;
    // ws usage ~= 77 MB

    dgru_wcvt<<<dim3(384), dim3(256), 0, stream>>>(W_z, W_r, U_r, W_h, w16);

    dgru_pre<<<dim3(NBLK), dim3(256), 0, stream>>>(
        fmess, wz16, wr16, wh16, ur16, b_z, b_h, b_Ur,
        fmess16, pre_r16, h16, uh16);

    for (int it = 1; it < 5; ++it) {
        dgru_gather<<<dim3(NM / 8), dim3(256), 0, stream>>>(
            h16, uh16, bgraph, pre_r16, sh16, sg16);
        dgru_zh<<<dim3(NBLK), dim3(256), 0, stream>>>(
            fmess16, sh16, sg16, wz16, wh16, ur16, b_z, b_h, b_Ur,
            h16, uh16, hout, (it == 4) ? 1 : 0);
    }
}

// Round 18
// 344.242 us; speedup vs baseline: 1.4028x; 1.1167x over previous
//
#include <hip/hip_runtime.h>
#include <hip/hip_bf16.h>

#define NM 50000
#define HD 128
#define KNEI 8
#define BM 32
#define SPAD 136
#define NBLK ((NM + BM - 1) / BM)   // 1563
#define NH ((size_t)NM * (size_t)HD)

typedef float  fx4   __attribute__((ext_vector_type(4)));
typedef short  s16x8 __attribute__((ext_vector_type(8)));
typedef short  s16x4 __attribute__((ext_vector_type(4)));

__device__ __forceinline__ float sigm_f(float x) {
    return __builtin_amdgcn_rcpf(1.0f + __expf(-x));
}
__device__ __forceinline__ float tanh_f(float x) {
    return 2.0f * sigm_f(2.0f * x) - 1.0f;
}
__device__ __forceinline__ unsigned short f2b(float f) {
    __hip_bfloat16 h = __float2bfloat16(f);
    return __builtin_bit_cast(unsigned short, h);
}
__device__ __forceinline__ float b2f(unsigned short u) {
    __hip_bfloat16 h = __builtin_bit_cast(__hip_bfloat16, u);
    return __bfloat162float(h);
}

#define MFMA16(a, b, c) __builtin_amdgcn_mfma_f32_16x16x32_bf16(a, b, c, 0, 0, 0)

// ---- register B-fragments from global (L2-hot weights); wave owns 2 col-frags ----
__device__ __forceinline__ void load_bfrag(const unsigned short* __restrict__ W,
                                           int ldw, int woff, int nf0, int l,
                                           s16x8 (&bf)[2][4])
{
    #pragma unroll
    for (int j = 0; j < 2; ++j) {
        const unsigned short* p =
            W + (size_t)((nf0 + j) * 16 + (l & 15)) * ldw + woff + ((l >> 4) << 3);
        #pragma unroll
        for (int ks = 0; ks < 4; ++ks)
            bf[j][ks] = *(const s16x8*)(p + ks * 32);
    }
}

// acc[rb][j] += A_tile(LDS, 32 rows) @ bf[j]^T over K=128 (ks ascending)
__device__ __forceinline__ void pass(const unsigned short (*As)[SPAD],
                                     const s16x8 (&bf)[2][4],
                                     int l, fx4 (&acc)[2][2])
{
    const int kq = (l >> 4) << 3;
    #pragma unroll
    for (int ks = 0; ks < 4; ++ks)
        #pragma unroll
        for (int rb = 0; rb < 2; ++rb) {
            const s16x8 a = *(const s16x8*)&As[rb * 16 + (l & 15)][ks * 32 + kq];
            acc[rb][0] = MFMA16(a, bf[0][ks], acc[rb][0]);
            acc[rb][1] = MFMA16(a, bf[1][ks], acc[rb][1]);
        }
}

#define ZACC2(acc) { _Pragma("unroll") for (int z_ = 0; z_ < 2; ++z_) { \
                     acc[z_][0] = (fx4)0.0f; acc[z_][1] = (fx4)0.0f; } }

// ---- staging / writeback (BM=32 rows; 256 threads stage, 128 threads copy out) ----
__device__ __forceinline__ void stage_A32(const float* __restrict__ A, int row0,
                                          unsigned short (*As)[SPAD], int tid)
{
    const int r  = tid & 31;
    const int c0 = (tid >> 5) << 4;    // 16-float chunks
    int gr = row0 + r; if (gr >= NM) gr = NM - 1;
    const float* ap = A + (size_t)gr * HD + c0;
    #pragma unroll
    for (int j = 0; j < 16; j += 8) {
        s16x8 s;
        #pragma unroll
        for (int q = 0; q < 8; ++q) s[q] = (short)f2b(ap[j + q]);
        *(s16x8*)&As[r][c0 + j] = s;
    }
}

__device__ __forceinline__ void stage_A16(const unsigned short* __restrict__ A16, int row0,
                                          unsigned short (*As)[SPAD], int tid)
{
    const int r  = tid & 31;
    const int c0 = (tid >> 5) << 4;    // 16-short chunks
    int gr = row0 + r; if (gr >= NM) gr = NM - 1;
    const unsigned short* ap = A16 + (size_t)gr * HD + c0;
    *(s16x8*)&As[r][c0]     = *(const s16x8*)ap;
    *(s16x8*)&As[r][c0 + 8] = *(const s16x8*)(ap + 8);
}

// 128 threads: 64B per thread (R13's proven write-combine pattern)
__device__ __forceinline__ void lds_to_g16(const unsigned short (*L)[SPAD], int row0,
                                           unsigned short* __restrict__ G, int tid)
{
    if (tid >= 128) return;
    const int r  = tid & 31;
    const int c0 = (tid >> 5) << 5;    // 32-short chunks
    const int gr = row0 + r;
    if (gr >= NM) return;
    #pragma unroll
    for (int j = 0; j < 32; j += 8)
        *(s16x8*)&G[(size_t)gr * HD + c0 + j] = *(const s16x8*)&L[r][c0 + j];
}

// ---------- weight fp32 -> bf16 conversion ----------
__global__ __launch_bounds__(256)
void dgru_wcvt(const float* __restrict__ Wz, const float* __restrict__ Wr,
               const float* __restrict__ Ur, const float* __restrict__ Wh,
               unsigned short* __restrict__ w16)
{
    const int i = blockIdx.x * 256 + threadIdx.x;
    float v;
    if      (i < 32768) v = Wz[i];
    else if (i < 49152) v = Wr[i - 32768];
    else if (i < 65536) v = Ur[i - 49152];
    else                v = Wh[i - 65536];
    w16[i] = f2b(v);
}

// ---------- pre: fmess16 + pre_r16 + h0 + Uh0 ----------
__global__ __launch_bounds__(256, 4)
void dgru_pre(const float* __restrict__ fmess,
              const unsigned short* __restrict__ wz16,
              const unsigned short* __restrict__ wr16,
              const unsigned short* __restrict__ wh16,
              const unsigned short* __restrict__ ur16,
              const float* __restrict__ bz, const float* __restrict__ bh,
              const float* __restrict__ bur,
              unsigned short* __restrict__ fmess16,
              unsigned short* __restrict__ pre_r16,
              unsigned short* __restrict__ h16, unsigned short* __restrict__ uh16)
{
    __shared__ unsigned short AsF[BM][SPAD];
    __shared__ unsigned short AsX[BM][SPAD];
    const int tid  = threadIdx.x;
    const int row0 = blockIdx.x * BM;
    const int l    = tid & 63;
    const int nf0  = (tid >> 6) << 1;
    const int col0 = nf0 * 16 + (l & 15);
    const int rq   = (l >> 4) << 2;

    s16x8 bfA[2][4], bfB[2][4];
    load_bfrag(wz16, 2 * HD, 0, nf0, l, bfA);   // Wz1
    load_bfrag(wr16, HD, 0, nf0, l, bfB);       // Wr
    stage_A32(fmess, row0, AsF, tid);
    __syncthreads();                            // S1

    lds_to_g16(AsF, row0, fmess16, tid);        // persist bf16 fmess

    fx4 zacc[2][2]; ZACC2(zacc);
    pass(AsF, bfA, l, zacc);                    // fmess @ Wz1
    load_bfrag(wh16, 2 * HD, 0, nf0, l, bfA);   // Wh1
    {
        fx4 racc[2][2]; ZACC2(racc);
        pass(AsF, bfB, l, racc);                // fmess @ Wr
        #pragma unroll
        for (int rb = 0; rb < 2; ++rb)
            #pragma unroll
            for (int j = 0; j < 2; ++j)
                #pragma unroll
                for (int q = 0; q < 4; ++q)
                    AsX[rb * 16 + rq + q][col0 + j * 16] = f2b(racc[rb][j][q]);
    }
    __syncthreads();                            // S2
    lds_to_g16(AsX, row0, pre_r16, tid);

    fx4 hacc[2][2]; ZACC2(hacc);
    pass(AsF, bfA, l, hacc);                    // fmess @ Wh1
    load_bfrag(ur16, HD, 0, nf0, l, bfB);       // Ur
    #pragma unroll
    for (int rb = 0; rb < 2; ++rb)
        #pragma unroll
        for (int j = 0; j < 2; ++j) {
            const float bvz = bz[col0 + j * 16];
            const float bvh = bh[col0 + j * 16];
            #pragma unroll
            for (int q = 0; q < 4; ++q) {
                const int gr = row0 + rb * 16 + rq + q;
                float h0 = sigm_f(zacc[rb][j][q] + bvz) * tanh_f(hacc[rb][j][q] + bvh);
                if (gr == 0) h0 = 0.0f;
                hacc[rb][j][q] = h0;
            }
        }
    __syncthreads();                            // S3: pre_r copy readers done
    #pragma unroll
    for (int rb = 0; rb < 2; ++rb)
        #pragma unroll
        for (int j = 0; j < 2; ++j)
            #pragma unroll
            for (int q = 0; q < 4; ++q)
                AsX[rb * 16 + rq + q][col0 + j * 16] = f2b(hacc[rb][j][q]);
    __syncthreads();                            // S4
    lds_to_g16(AsX, row0, h16, tid);
    {
        fx4 uacc[2][2]; ZACC2(uacc);
        pass(AsX, bfB, l, uacc);                // h0 @ Ur
        #pragma unroll
        for (int rb = 0; rb < 2; ++rb)
            #pragma unroll
            for (int j = 0; j < 2; ++j) {
                const float bv = bur[col0 + j * 16];
                #pragma unroll
                for (int q = 0; q < 4; ++q)
                    AsF[rb * 16 + rq + q][col0 + j * 16] = f2b(uacc[rb][j][q] + bv);
            }
    }
    __syncthreads();                            // S5
    lds_to_g16(AsF, row0, uh16, tid);
}

// ---------- gather (unchanged, standalone high-occupancy) ----------
__global__ __launch_bounds__(256)
void dgru_gather(const unsigned short* __restrict__ h16,
                 const unsigned short* __restrict__ uh16,
                 const int* __restrict__ bgraph,
                 const unsigned short* __restrict__ pre_r16,
                 unsigned short* __restrict__ sh16, unsigned short* __restrict__ sg16)
{
    const int tid = threadIdx.x;
    const int n   = blockIdx.x * 8 + (tid >> 5);
    const int d0  = (tid & 31) << 2;

    const int4* bg = (const int4*)(bgraph + (size_t)n * KNEI);
    const int4 b0 = bg[0], b1 = bg[1];
    const int idx[KNEI] = {b0.x, b0.y, b0.z, b0.w, b1.x, b1.y, b1.z, b1.w};

    s16x4 hr[KNEI], ur[KNEI];
    #pragma unroll
    for (int k = 0; k < KNEI; ++k)
        hr[k] = *(const s16x4*)&h16[(size_t)idx[k] * HD + d0];
    #pragma unroll
    for (int k = 0; k < KNEI; ++k)
        ur[k] = *(const s16x4*)&uh16[(size_t)idx[k] * HD + d0];
    const s16x4 prb = *(const s16x4*)&pre_r16[(size_t)n * HD + d0];
    float pr[4];
    #pragma unroll
    for (int j = 0; j < 4; ++j) pr[j] = b2f((unsigned short)prb[j]);

    float sh[4] = {0.f, 0.f, 0.f, 0.f};
    float sg[4] = {0.f, 0.f, 0.f, 0.f};
    #pragma unroll
    for (int k = 0; k < KNEI; ++k) {
        #pragma unroll
        for (int j = 0; j < 4; ++j) {
            const float hv = b2f((unsigned short)hr[k][j]);
            const float uv = b2f((unsigned short)ur[k][j]);
            sh[j] += hv;
            sg[j] = fmaf(sigm_f(pr[j] + uv), hv, sg[j]);
        }
    }
    s16x4 osh, osg;
    #pragma unroll
    for (int j = 0; j < 4; ++j) {
        osh[j] = (short)f2b(sh[j]);
        osg[j] = (short)f2b(sg[j]);
    }
    const size_t o = (size_t)n * HD + d0;
    *(s16x4*)&sh16[o] = osh;
    *(s16x4*)&sg16[o] = osg;
}

// ---------- zh (R13 dataflow, BM=32): z + GRU update + next Uh ----------
__global__ __launch_bounds__(256, 4)
void dgru_zh(const unsigned short* __restrict__ fmess16,
             const unsigned short* __restrict__ sh16,
             const unsigned short* __restrict__ sg16,
             const unsigned short* __restrict__ wz16,
             const unsigned short* __restrict__ wh16,
             const unsigned short* __restrict__ ur16,
             const float* __restrict__ bz, const float* __restrict__ bh,
             const float* __restrict__ bur,
             unsigned short* __restrict__ h16, unsigned short* __restrict__ uh16,
             float* __restrict__ hout, int last)
{
    __shared__ unsigned short AsF[BM][SPAD];   // fmess tile; later new h
    __shared__ unsigned short AsX[BM][SPAD];   // sum_h, then sum_g, then Uh
    const int tid  = threadIdx.x;
    const int row0 = blockIdx.x * BM;
    const int l    = tid & 63;
    const int nf0  = (tid >> 6) << 1;
    const int col0 = nf0 * 16 + (l & 15);
    const int rq   = (l >> 4) << 2;

    s16x8 bfA[2][4], bfB[2][4];
    load_bfrag(wz16, 2 * HD, 0,  nf0, l, bfA);  // Wz1
    load_bfrag(wz16, 2 * HD, HD, nf0, l, bfB);  // Wz2
    stage_A16(fmess16, row0, AsF, tid);
    stage_A16(sh16,    row0, AsX, tid);
    __syncthreads();                            // S1

    // z = sigmoid(fmess@Wz1 + sum_h@Wz2 + bz); sum_h captured packed
    fx4 zacc[2][2]; ZACC2(zacc);
    pass(AsF, bfA, l, zacc);
    pass(AsX, bfB, l, zacc);
    s16x4 shp[2][2];
    #pragma unroll
    for (int rb = 0; rb < 2; ++rb)
        #pragma unroll
        for (int j = 0; j < 2; ++j) {
            const float bv = bz[col0 + j * 16];
            #pragma unroll
            for (int q = 0; q < 4; ++q) {
                shp[rb][j][q] = (short)AsX[rb * 16 + rq + q][col0 + j * 16];
                zacc[rb][j][q] = sigm_f(zacc[rb][j][q] + bv);   // zacc := z
            }
        }
    load_bfrag(wh16, 2 * HD, 0,  nf0, l, bfA);  // Wh1
    load_bfrag(wh16, 2 * HD, HD, nf0, l, bfB);  // Wh2
    __syncthreads();                            // S2: AsX readers done
    stage_A16(sg16, row0, AsX, tid);
    __syncthreads();                            // S3

    // h = (1-z)*sum_h + z*tanh(fmess@Wh1 + sum_g@Wh2 + bh)
    fx4 hacc[2][2]; ZACC2(hacc);
    pass(AsF, bfA, l, hacc);
    pass(AsX, bfB, l, hacc);
    #pragma unroll
    for (int rb = 0; rb < 2; ++rb)
        #pragma unroll
        for (int j = 0; j < 2; ++j) {
            const float bv = bh[col0 + j * 16];
            #pragma unroll
            for (int q = 0; q < 4; ++q) {
                const int gr = row0 + rb * 16 + rq + q;
                const float zz = zacc[rb][j][q];
                const float sv = b2f((unsigned short)shp[rb][j][q]);
                float o = (1.0f - zz) * sv + zz * tanh_f(hacc[rb][j][q] + bv);
                if (gr == 0) o = 0.0f;
                hacc[rb][j][q] = o;
            }
        }
    if (last) {
        #pragma unroll
        for (int rb = 0; rb < 2; ++rb)
            #pragma unroll
            for (int j = 0; j < 2; ++j)
                #pragma unroll
                for (int q = 0; q < 4; ++q) {
                    const int gr = row0 + rb * 16 + rq + q;
                    if (gr < NM) hout[(size_t)gr * HD + col0 + j * 16] = hacc[rb][j][q];
                }
        return;
    }
    load_bfrag(ur16, HD, 0, nf0, l, bfA);       // Ur
    __syncthreads();                            // S4: AsF/AsX readers done
    #pragma unroll
    for (int rb = 0; rb < 2; ++rb)
        #pragma unroll
        for (int j = 0; j < 2; ++j)
            #pragma unroll
            for (int q = 0; q < 4; ++q)
                AsF[rb * 16 + rq + q][col0 + j * 16] = f2b(hacc[rb][j][q]);
    __syncthreads();                            // S5
    lds_to_g16(AsF, row0, h16, tid);
    {
        fx4 uacc[2][2]; ZACC2(uacc);
        pass(AsF, bfA, l, uacc);                // h @ Ur
        #pragma unroll
        for (int rb = 0; rb < 2; ++rb)
            #pragma unroll
            for (int j = 0; j < 2; ++j) {
                const float bv = bur[col0 + j * 16];
                #pragma unroll
                for (int q = 0; q < 4; ++q)
                    AsX[rb * 16 + rq + q][col0 + j * 16] = f2b(uacc[rb][j][q] + bv);
            }
    }
    __syncthreads();                            // S6
    lds_to_g16(AsX, row0, uh16, tid);
}

extern "C" void kernel_launch(void* const* d_in, const int* in_sizes, int n_in,
                              void* d_out, int out_size, void* d_ws, size_t ws_size,
                              hipStream_t stream) {
    const float* fmess  = (const float*)d_in[0];
    const int*   bgraph = (const int*)  d_in[1];
    const float* W_z    = (const float*)d_in[2];
    const float* b_z    = (const float*)d_in[3];
    const float* W_r    = (const float*)d_in[4];
    const float* U_r    = (const float*)d_in[5];
    const float* b_Ur   = (const float*)d_in[6];
    const float* W_h    = (const float*)d_in[7];
    const float* b_h    = (const float*)d_in[8];

    unsigned short* ws16 = (unsigned short*)d_ws;
    unsigned short* fmess16 = ws16;
    unsigned short* pre_r16 = ws16 + NH;
    unsigned short* h16     = ws16 + 2 * NH;
    unsigned short* uh16    = ws16 + 3 * NH;
    unsigned short* sh16    = ws16 + 4 * NH;
    unsigned short* sg16    = ws16 + 5 * NH;
    unsigned short* w16     = ws16 + 6 * NH;
    unsigned short* wz16 = w16;                // [128][256]
    unsigned short* wr16 = w16 + 32768;        // [128][128]
    unsigned short* ur16 = w16 + 49152;        // [128][128]
    unsigned short* wh16 = w16 + 65536;        // [128][256]
    float* hout = (float*)d_out;
    // ws usage ~= 77 MB

    dgru_wcvt<<<dim3(384), dim3(256), 0, stream>>>(W_z, W_r, U_r, W_h, w16);

    dgru_pre<<<dim3(NBLK), dim3(256), 0, stream>>>(
        fmess, wz16, wr16, wh16, ur16, b_z, b_h, b_Ur,
        fmess16, pre_r16, h16, uh16);

    for (int it = 1; it < 5; ++it) {
        dgru_gather<<<dim3(NM / 8), dim3(256), 0, stream>>>(
            h16, uh16, bgraph, pre_r16, sh16, sg16);
        dgru_zh<<<dim3(NBLK), dim3(256), 0, stream>>>(
            fmess16, sh16, sg16, wz16, wh16, ur16, b_z, b_h, b_Ur,
            h16, uh16, hout, (it == 4) ? 1 : 0);
    }
}

// Round 19
// 275.185 us; speedup vs baseline: 1.7548x; 1.2509x over previous
//
#include <hip/hip_runtime.h>
#include <hip/hip_bf16.h>

#define NM 50000
#define HD 128
#define KNEI 8
#define BM 64
#define SPAD 136
#define NBLK ((NM + BM - 1) / BM)   // 782
#define NH ((size_t)NM * (size_t)HD)
#define FRAG 8192                   // fragment elems per block (64 x 128)

typedef float  fx4   __attribute__((ext_vector_type(4)));
typedef short  s16x8 __attribute__((ext_vector_type(8)));
typedef short  s16x4 __attribute__((ext_vector_type(4)));

__device__ __forceinline__ float sigm_f(float x) {
    return __builtin_amdgcn_rcpf(1.0f + __expf(-x));
}
__device__ __forceinline__ float tanh_f(float x) {
    return 2.0f * sigm_f(2.0f * x) - 1.0f;
}
__device__ __forceinline__ unsigned short f2b(float f) {
    __hip_bfloat16 h = __float2bfloat16(f);
    return __builtin_bit_cast(unsigned short, h);
}
__device__ __forceinline__ float b2f(unsigned short u) {
    __hip_bfloat16 h = __builtin_bit_cast(__hip_bfloat16, u);
    return __bfloat162float(h);
}

#define MFMA16(a, b, c) __builtin_amdgcn_mfma_f32_16x16x32_bf16(a, b, c, 0, 0, 0)

// ---- register B-fragments from global (L2-hot weights) ----
__device__ __forceinline__ void load_bfrag(const unsigned short* __restrict__ W,
                                           int ldw, int woff, int nf0, int l,
                                           s16x8 (&bf)[2][4])
{
    #pragma unroll
    for (int j = 0; j < 2; ++j) {
        const unsigned short* p =
            W + (size_t)((nf0 + j) * 16 + (l & 15)) * ldw + woff + ((l >> 4) << 3);
        #pragma unroll
        for (int ks = 0; ks < 4; ++ks)
            bf[j][ks] = *(const s16x8*)(p + ks * 32);
    }
}

// acc[rb][j] += A_tile(LDS) @ bf[j]^T over K=128 (ks ascending)
__device__ __forceinline__ void pass(const unsigned short (*As)[SPAD],
                                     const s16x8 (&bf)[2][4],
                                     int l, fx4 (&acc)[4][2])
{
    const int kq = (l >> 4) << 3;
    #pragma unroll
    for (int ks = 0; ks < 4; ++ks)
        #pragma unroll
        for (int rb = 0; rb < 4; ++rb) {
            const s16x8 a = *(const s16x8*)&As[rb * 16 + (l & 15)][ks * 32 + kq];
            acc[rb][0] = MFMA16(a, bf[0][ks], acc[rb][0]);
            acc[rb][1] = MFMA16(a, bf[1][ks], acc[rb][1]);
        }
}

#define ZACC2(acc) { _Pragma("unroll") for (int z_ = 0; z_ < 4; ++z_) { \
                     acc[z_][0] = (fx4)0.0f; acc[z_][1] = (fx4)0.0f; } }

// fragment-linear bf16 pre-act address (elems): blk*FRAG + fid*256 + l*4
__device__ __forceinline__ size_t faddr(int blk, int nf0, int j, int rb, int l) {
    return (size_t)blk * FRAG + (size_t)((nf0 + j) * 4 + rb) * 256 + (size_t)l * 4;
}

// ---- 256-thread A staging / writeback (BM=64) ----
__device__ __forceinline__ void stage_A32(const float* __restrict__ A, int row0,
                                          unsigned short (*As)[SPAD], int tid)
{
    const int r  = tid & 63;
    const int c0 = (tid >> 6) << 5;
    int gr = row0 + r; if (gr >= NM) gr = NM - 1;
    const float* ap = A + (size_t)gr * HD + c0;
    #pragma unroll
    for (int j = 0; j < 32; j += 8) {
        s16x8 s;
        #pragma unroll
        for (int q = 0; q < 8; ++q) s[q] = (short)f2b(ap[j + q]);
        *(s16x8*)&As[r][c0 + j] = s;
    }
}

__device__ __forceinline__ void stage_A16(const unsigned short* __restrict__ A16, int row0,
                                          unsigned short (*As)[SPAD], int tid)
{
    const int r  = tid & 63;
    const int c0 = (tid >> 6) << 5;
    int gr = row0 + r; if (gr >= NM) gr = NM - 1;
    const unsigned short* ap = A16 + (size_t)gr * HD + c0;
    #pragma unroll
    for (int j = 0; j < 32; j += 8)
        *(s16x8*)&As[r][c0 + j] = *(const s16x8*)(ap + j);
}

__device__ __forceinline__ void lds_to_g16(const unsigned short (*L)[SPAD], int row0,
                                           unsigned short* __restrict__ G, int tid)
{
    const int r  = tid & 63;
    const int c0 = (tid >> 6) << 5;
    const int gr = row0 + r;
    if (gr >= NM) return;
    #pragma unroll
    for (int j = 0; j < 32; j += 8)
        *(s16x8*)&G[(size_t)gr * HD + c0 + j] = *(const s16x8*)&L[r][c0 + j];
}

// ---------- weight fp32 -> bf16 conversion ----------
__global__ __launch_bounds__(256)
void dgru_wcvt(const float* __restrict__ Wz, const float* __restrict__ Wr,
               const float* __restrict__ Ur, const float* __restrict__ Wh,
               unsigned short* __restrict__ w16)
{
    const int i = blockIdx.x * 256 + threadIdx.x;
    float v;
    if      (i < 32768) v = Wz[i];
    else if (i < 49152) v = Wr[i - 32768];
    else if (i < 65536) v = Ur[i - 49152];
    else                v = Wh[i - 65536];
    w16[i] = f2b(v);
}

// ---------- pre: pre_z16/pre_hf16 (fragment bf16, direct) + pre_r16 + h0 + Uh0 ----------
__global__ __launch_bounds__(256, 3)
void dgru_pre(const float* __restrict__ fmess,
              const unsigned short* __restrict__ wz16,
              const unsigned short* __restrict__ wr16,
              const unsigned short* __restrict__ wh16,
              const unsigned short* __restrict__ ur16,
              const float* __restrict__ bz, const float* __restrict__ bh,
              const float* __restrict__ bur,
              unsigned short* __restrict__ pre_z16,
              unsigned short* __restrict__ pre_hf16,
              unsigned short* __restrict__ pre_r16,
              unsigned short* __restrict__ h16, unsigned short* __restrict__ uh16)
{
    __shared__ unsigned short AsF[BM][SPAD];
    __shared__ unsigned short AsX[BM][SPAD];
    const int tid  = threadIdx.x;
    const int blk  = blockIdx.x;
    const int row0 = blk * BM;
    const int l    = tid & 63;
    const int nf0  = (tid >> 6) << 1;
    const int col0 = nf0 * 16 + (l & 15);
    const int rq   = (l >> 4) << 2;

    s16x8 bfA[2][4], bfB[2][4];
    load_bfrag(wz16, 2 * HD, 0, nf0, l, bfA);   // Wz1
    load_bfrag(wr16, HD, 0, nf0, l, bfB);       // Wr
    stage_A32(fmess, row0, AsF, tid);
    __syncthreads();                            // S1

    fx4 zacc[4][2]; ZACC2(zacc);
    pass(AsF, bfA, l, zacc);                    // fmess @ Wz1
    load_bfrag(wh16, 2 * HD, 0, nf0, l, bfA);   // Wh1
    {
        fx4 racc[4][2]; ZACC2(racc);
        pass(AsF, bfB, l, racc);                // fmess @ Wr
        #pragma unroll
        for (int rb = 0; rb < 4; ++rb)
            #pragma unroll
            for (int j = 0; j < 2; ++j)
                #pragma unroll
                for (int q = 0; q < 4; ++q)
                    AsX[rb * 16 + rq + q][col0 + j * 16] = f2b(racc[rb][j][q]);
    }
    __syncthreads();                            // S2
    lds_to_g16(AsX, row0, pre_r16, tid);        // pre_r row-major (gather reads it)

    fx4 hacc[4][2]; ZACC2(hacc);
    pass(AsF, bfA, l, hacc);                    // fmess @ Wh1
    load_bfrag(ur16, HD, 0, nf0, l, bfB);       // Ur
    #pragma unroll
    for (int rb = 0; rb < 4; ++rb)
        #pragma unroll
        for (int j = 0; j < 2; ++j) {
            const float bvz = bz[col0 + j * 16];
            const float bvh = bh[col0 + j * 16];
            s16x4 pz, ph;
            #pragma unroll
            for (int q = 0; q < 4; ++q) {
                const float zlog = zacc[rb][j][q] + bvz;
                const float hlog = hacc[rb][j][q] + bvh;
                pz[q] = (short)f2b(zlog);
                ph[q] = (short)f2b(hlog);
                const int gr = row0 + rb * 16 + rq + q;
                float h0 = sigm_f(zlog) * tanh_f(hlog);
                if (gr == 0) h0 = 0.0f;
                hacc[rb][j][q] = h0;
            }
            // direct coalesced fragment-linear stores (8B/lane)
            *(s16x4*)&pre_z16[faddr(blk, nf0, j, rb, l)]  = pz;
            *(s16x4*)&pre_hf16[faddr(blk, nf0, j, rb, l)] = ph;
        }
    __syncthreads();                            // S3: pre_r copy readers done
    #pragma unroll
    for (int rb = 0; rb < 4; ++rb)
        #pragma unroll
        for (int j = 0; j < 2; ++j)
            #pragma unroll
            for (int q = 0; q < 4; ++q)
                AsX[rb * 16 + rq + q][col0 + j * 16] = f2b(hacc[rb][j][q]);
    __syncthreads();                            // S4
    lds_to_g16(AsX, row0, h16, tid);
    {
        fx4 uacc[4][2]; ZACC2(uacc);
        pass(AsX, bfB, l, uacc);                // h0 @ Ur
        #pragma unroll
        for (int rb = 0; rb < 4; ++rb)
            #pragma unroll
            for (int j = 0; j < 2; ++j) {
                const float bv = bur[col0 + j * 16];
                #pragma unroll
                for (int q = 0; q < 4; ++q)
                    AsF[rb * 16 + rq + q][col0 + j * 16] = f2b(uacc[rb][j][q] + bv);
            }
    }
    __syncthreads();                            // S5
    lds_to_g16(AsF, row0, uh16, tid);
}

// ---------- gather (standalone high-occupancy, unchanged) ----------
__global__ __launch_bounds__(256)
void dgru_gather(const unsigned short* __restrict__ h16,
                 const unsigned short* __restrict__ uh16,
                 const int* __restrict__ bgraph,
                 const unsigned short* __restrict__ pre_r16,
                 unsigned short* __restrict__ sh16, unsigned short* __restrict__ sg16)
{
    const int tid = threadIdx.x;
    const int n   = blockIdx.x * 8 + (tid >> 5);
    const int d0  = (tid & 31) << 2;

    const int4* bg = (const int4*)(bgraph + (size_t)n * KNEI);
    const int4 b0 = bg[0], b1 = bg[1];
    const int idx[KNEI] = {b0.x, b0.y, b0.z, b0.w, b1.x, b1.y, b1.z, b1.w};

    s16x4 hr[KNEI], ur[KNEI];
    #pragma unroll
    for (int k = 0; k < KNEI; ++k)
        hr[k] = *(const s16x4*)&h16[(size_t)idx[k] * HD + d0];
    #pragma unroll
    for (int k = 0; k < KNEI; ++k)
        ur[k] = *(const s16x4*)&uh16[(size_t)idx[k] * HD + d0];
    const s16x4 prb = *(const s16x4*)&pre_r16[(size_t)n * HD + d0];
    float pr[4];
    #pragma unroll
    for (int j = 0; j < 4; ++j) pr[j] = b2f((unsigned short)prb[j]);

    float sh[4] = {0.f, 0.f, 0.f, 0.f};
    float sg[4] = {0.f, 0.f, 0.f, 0.f};
    #pragma unroll
    for (int k = 0; k < KNEI; ++k) {
        #pragma unroll
        for (int j = 0; j < 4; ++j) {
            const float hv = b2f((unsigned short)hr[k][j]);
            const float uv = b2f((unsigned short)ur[k][j]);
            sh[j] += hv;
            sg[j] = fmaf(sigm_f(pr[j] + uv), hv, sg[j]);
        }
    }
    s16x4 osh, osg;
    #pragma unroll
    for (int j = 0; j < 4; ++j) {
        osh[j] = (short)f2b(sh[j]);
        osg[j] = (short)f2b(sg[j]);
    }
    const size_t o = (size_t)n * HD + d0;
    *(s16x4*)&sh16[o] = osh;
    *(s16x4*)&sg16[o] = osg;
}

// ---------- zh: precomputed bf16 pre-acts, reg-weights, 3 passes, 4 barriers ----------
__global__ __launch_bounds__(256, 3)
void dgru_zh(const unsigned short* __restrict__ pre_z16,
             const unsigned short* __restrict__ pre_hf16,
             const unsigned short* __restrict__ sh16,
             const unsigned short* __restrict__ sg16,
             const unsigned short* __restrict__ wz16,
             const unsigned short* __restrict__ wh16,
             const unsigned short* __restrict__ ur16,
             const float* __restrict__ bur,
             unsigned short* __restrict__ h16, unsigned short* __restrict__ uh16,
             float* __restrict__ hout, int last)
{
    __shared__ unsigned short AsH[BM][SPAD];   // sum_h tile; later new h
    __shared__ unsigned short AsX[BM][SPAD];   // sum_g tile; later Uh
    const int tid  = threadIdx.x;
    const int blk  = blockIdx.x;
    const int row0 = blk * BM;
    const int l    = tid & 63;
    const int nf0  = (tid >> 6) << 1;
    const int col0 = nf0 * 16 + (l & 15);
    const int rq   = (l >> 4) << 2;

    s16x8 bfA[2][4], bfB[2][4];
    load_bfrag(wz16, 2 * HD, HD, nf0, l, bfA);  // Wz2
    load_bfrag(wh16, 2 * HD, HD, nf0, l, bfB);  // Wh2
    stage_A16(sh16, row0, AsH, tid);
    stage_A16(sg16, row0, AsX, tid);
    __syncthreads();                            // S1

    // z = sigmoid(pre_z16 + sum_h@Wz2)
    fx4 zacc[4][2]; ZACC2(zacc);
    pass(AsH, bfA, l, zacc);
    // h = (1-z)*sum_h + z*tanh(pre_hf16 + sum_g@Wh2)
    fx4 hacc[4][2]; ZACC2(hacc);
    pass(AsX, bfB, l, hacc);
    load_bfrag(ur16, HD, 0, nf0, l, bfA);       // Ur (bfA free after z-pass)
    #pragma unroll
    for (int rb = 0; rb < 4; ++rb)
        #pragma unroll
        for (int j = 0; j < 2; ++j) {
            const s16x4 pz = *(const s16x4*)&pre_z16[faddr(blk, nf0, j, rb, l)];
            const s16x4 ph = *(const s16x4*)&pre_hf16[faddr(blk, nf0, j, rb, l)];
            #pragma unroll
            for (int q = 0; q < 4; ++q) {
                const int gr = row0 + rb * 16 + rq + q;
                const float zz = sigm_f(b2f((unsigned short)pz[q]) + zacc[rb][j][q]);
                const float sv = b2f(AsH[rb * 16 + rq + q][col0 + j * 16]);
                float o = (1.0f - zz) * sv
                        + zz * tanh_f(b2f((unsigned short)ph[q]) + hacc[rb][j][q]);
                if (gr == 0) o = 0.0f;
                hacc[rb][j][q] = o;
            }
        }
    if (last) {
        #pragma unroll
        for (int rb = 0; rb < 4; ++rb)
            #pragma unroll
            for (int j = 0; j < 2; ++j)
                #pragma unroll
                for (int q = 0; q < 4; ++q) {
                    const int gr = row0 + rb * 16 + rq + q;
                    if (gr < NM) hout[(size_t)gr * HD + col0 + j * 16] = hacc[rb][j][q];
                }
        return;
    }
    __syncthreads();                            // S2: all AsH/AsX readers done
    #pragma unroll
    for (int rb = 0; rb < 4; ++rb)
        #pragma unroll
        for (int j = 0; j < 2; ++j)
            #pragma unroll
            for (int q = 0; q < 4; ++q)
                AsH[rb * 16 + rq + q][col0 + j * 16] = f2b(hacc[rb][j][q]);
    __syncthreads();                            // S3: new-h tile complete
    lds_to_g16(AsH, row0, h16, tid);
    {
        fx4 uacc[4][2]; ZACC2(uacc);
        pass(AsH, bfA, l, uacc);                // h @ Ur
        #pragma unroll
        for (int rb = 0; rb < 4; ++rb)
            #pragma unroll
            for (int j = 0; j < 2; ++j) {
                const float bv = bur[col0 + j * 16];
                #pragma unroll
                for (int q = 0; q < 4; ++q)
                    AsX[rb * 16 + rq + q][col0 + j * 16] = f2b(uacc[rb][j][q] + bv);
            }
    }
    __syncthreads();                            // S4: Uh tile complete
    lds_to_g16(AsX, row0, uh16, tid);
}

extern "C" void kernel_launch(void* const* d_in, const int* in_sizes, int n_in,
                              void* d_out, int out_size, void* d_ws, size_t ws_size,
                              hipStream_t stream) {
    const float* fmess  = (const float*)d_in[0];
    const int*   bgraph = (const int*)  d_in[1];
    const float* W_z    = (const float*)d_in[2];
    const float* b_z    = (const float*)d_in[3];
    const float* W_r    = (const float*)d_in[4];
    const float* U_r    = (const float*)d_in[5];
    const float* b_Ur   = (const float*)d_in[6];
    const float* W_h    = (const float*)d_in[7];
    const float* b_h    = (const float*)d_in[8];

    unsigned short* ws16 = (unsigned short*)d_ws;
    const size_t FPAD = (size_t)NBLK * FRAG;     // 6406144 elems
    unsigned short* pre_z16  = ws16;             // fragment-linear
    unsigned short* pre_hf16 = ws16 + FPAD;      // fragment-linear
    unsigned short* pre_r16  = ws16 + 2 * FPAD;  // row-major
    unsigned short* h16      = pre_r16 + NH;
    unsigned short* uh16     = h16 + NH;
    unsigned short* sh16     = uh16 + NH;
    unsigned short* sg16     = sh16 + NH;
    unsigned short* w16      = sg16 + NH;
    unsigned short* wz16 = w16;                  // [128][256]
    unsigned short* wr16 = w16 + 32768;          // [128][128]
    unsigned short* ur16 = w16 + 49152;          // [128][128]
    unsigned short* wh16 = w16 + 65536;          // [128][256]
    float* hout = (float*)d_out;
    // ws usage ~= 90 MB

    dgru_wcvt<<<dim3(384), dim3(256), 0, stream>>>(W_z, W_r, U_r, W_h, w16);

    dgru_pre<<<dim3(NBLK), dim3(256), 0, stream>>>(
        fmess, wz16, wr16, wh16, ur16, b_z, b_h, b_Ur,
        pre_z16, pre_hf16, pre_r16, h16, uh16);

    for (int it = 1; it < 5; ++it) {
        dgru_gather<<<dim3(NM / 8), dim3(256), 0, stream>>>(
            h16, uh16, bgraph, pre_r16, sh16, sg16);
        dgru_zh<<<dim3(NBLK), dim3(256), 0, stream>>>(
            pre_z16, pre_hf16, sh16, sg16, wz16, wh16, ur16, b_Ur,
            h16, uh16, hout, (it == 4) ? 1 : 0);
    }
}